// Round 8
// baseline (270.706 us; speedup 1.0000x reference)
//
#include <hip/hip_runtime.h>

// AssociativeMemoryStep — chunked linear attention, fully MFMA.
// Round 8 (= Round 6 kernel, resubmitted after two GPU timeouts): fold basis
// into per-stream weights (qkv = x @ Wq^T directly), m97-style GEMM
// (global_load_lds width=16, BK=64, linear LDS) for all GEMMs, x converted to
// bf16 once. 4-deep batched loads in the serial scan.
// B=4 T=4096 V=1024 F=128 C=256, chunk Tc=64 (G=64).

#define Bb 4
#define Tt 4096
#define Vv 1024
#define Ff 128
#define Cc 256
#define TC 64
#define Gg (Tt / TC)
#define QLD 768  // q|k|v row stride (elements)

typedef __attribute__((ext_vector_type(8))) short short8;
typedef __attribute__((ext_vector_type(4))) float f32x4;

__device__ __forceinline__ float dsigmoid(const float* p) {
    return 1.0f / (1.0f + expf(-p[0]));
}
__device__ __forceinline__ ushort f2bf(float f) {
    unsigned u = __float_as_uint(f);
    u = (u + 0x7FFFu + ((u >> 16) & 1u)) >> 16;
    return (ushort)u;
}
__device__ __forceinline__ float bf2f(ushort u) {
    return __uint_as_float(((unsigned)u) << 16);
}
__device__ __forceinline__ void gl_lds16(ushort* lds, const ushort* gp) {
    __builtin_amdgcn_global_load_lds(
        (const __attribute__((address_space(1))) unsigned int*)gp,
        (__attribute__((address_space(3))) unsigned int*)lds,
        16, 0, 0);
}

// ---------------------------------------------------------------- x -> bf16
__global__ __launch_bounds__(256) void convert_x(
    const float* __restrict__ x, ushort* __restrict__ xbf)
{
    const size_t total = (size_t)Bb * Tt * Vv;
    for (size_t i = ((size_t)blockIdx.x * 256 + threadIdx.x) * 8; i < total;
         i += (size_t)2048 * 256 * 8) {
        float4 a = *(const float4*)(x + i);
        float4 b = *(const float4*)(x + i + 4);
        union { ushort us[8]; int4 v; } o;
        o.us[0] = f2bf(a.x); o.us[1] = f2bf(a.y); o.us[2] = f2bf(a.z); o.us[3] = f2bf(a.w);
        o.us[4] = f2bf(b.x); o.us[5] = f2bf(b.y); o.us[6] = f2bf(b.z); o.us[7] = f2bf(b.w);
        *(int4*)(xbf + i) = o.v;
    }
}

// ---------------------------------------------------------------- weight prep
__global__ __launch_bounds__(256) void prep_weights(
    const float* __restrict__ basis, const float* __restrict__ qc,
    const float* __restrict__ kc, const float* __restrict__ vc,
    const float* __restrict__ oc,
    ushort* __restrict__ basisb,    // [1024][128] bf16 (straight convert)
    ushort* __restrict__ qkvc,      // [768][128]  bf16 concat(qc,kc,vc)
    ushort* __restrict__ ocb)       // [256][128]  bf16
{
    int i = blockIdx.x * 256 + threadIdx.x;
    if (i < Vv * Ff) basisb[i] = f2bf(basis[i]);
    if (i < 768 * Ff) {
        int ch = i >> 7;
        const float* src = ch < 256 ? qc : (ch < 512 ? kc : vc);
        qkvc[i] = f2bf(src[(ch & 255) * Ff + (i & 127)]);
    }
    if (i < Cc * Ff) ocb[i] = f2bf(oc[i]);
}

// ---------------------------------------------------------------- MFMA GEMM (m97 structure)
// C[M,N] = A[M,K] @ Bt[N,K]^T, A/Bt bf16 K-major. BM=BN=128, BK=64,
// 4 waves (2x2), 64x64/wave, global_load_lds width=16, linear LDS.
// OMODE: 0 = bf16 out, 1 = fp32 out * alpha.
template<int OMODE>
__global__ __launch_bounds__(256) void ggemm(
    const ushort* __restrict__ A, const ushort* __restrict__ Bt,
    void* __restrict__ Cp, int N_total, int K_total, int ldA,
    const float* __restrict__ alpha_ptr)
{
    __shared__ ushort Asm[128 * 64];
    __shared__ ushort Bsm[128 * 64];
    const int tid = threadIdx.x;
    const int row0 = blockIdx.x * 128, col0 = blockIdx.y * 128;
    const int l = tid & 63, w = tid >> 6;
    const int wr = (w >> 1) * 64, wc = (w & 1) * 64;
    const int lrow = l & 15, lk = l >> 4;

    f32x4 acc[4][4];
#pragma unroll
    for (int mi = 0; mi < 4; ++mi)
#pragma unroll
        for (int ni = 0; ni < 4; ++ni) {
            f32x4 z = {0.f, 0.f, 0.f, 0.f};
            acc[mi][ni] = z;
        }

    for (int k0 = 0; k0 < K_total; k0 += 64) {
#pragma unroll
        for (int call = 0; call < 4; ++call) {
            int ia = tid * 8 + call * 2048;          // shorts; lane-contig 16B
            int r = ia >> 6, c = ia & 63;
            gl_lds16(&Asm[ia], A + (size_t)(row0 + r) * ldA + k0 + c);
            gl_lds16(&Bsm[ia], Bt + (size_t)(col0 + r) * K_total + k0 + c);
        }
        __syncthreads();                              // drains vmcnt -> LDS ready
#pragma unroll
        for (int ks = 0; ks < 2; ++ks) {
            short8 af[4], bf[4];
#pragma unroll
            for (int mi = 0; mi < 4; ++mi)
                af[mi] = *(const short8*)&Asm[(wr + mi * 16 + lrow) * 64 + ks * 32 + lk * 8];
#pragma unroll
            for (int ni = 0; ni < 4; ++ni)
                bf[ni] = *(const short8*)&Bsm[(wc + ni * 16 + lrow) * 64 + ks * 32 + lk * 8];
#pragma unroll
            for (int mi = 0; mi < 4; ++mi)
#pragma unroll
                for (int ni = 0; ni < 4; ++ni)
                    acc[mi][ni] = __builtin_amdgcn_mfma_f32_16x16x32_bf16(
                        af[mi], bf[ni], acc[mi][ni], 0, 0, 0);
        }
        __syncthreads();
    }

    const float alpha = (OMODE == 1) ? alpha_ptr[0] : 1.0f;
#pragma unroll
    for (int mi = 0; mi < 4; ++mi)
#pragma unroll
        for (int ni = 0; ni < 4; ++ni)
#pragma unroll
            for (int r = 0; r < 4; ++r) {
                int row = row0 + wr + mi * 16 + lk * 4 + r;
                int col = col0 + wc + ni * 16 + lrow;
                size_t idx = (size_t)row * N_total + col;
                if (OMODE == 1) ((float*)Cp)[idx] = acc[mi][ni][r] * alpha;
                else ((ushort*)Cp)[idx] = f2bf(acc[mi][ni][r]);
            }
}

// ---------------------------------------------------------------- K/V transpose
// Kts[b][c][t] = d^{t&63} * K[b][t][c] ; Vt[b][c][t] = V[b][t][c]  (bf16)
__global__ __launch_bounds__(256) void transpose_kv(
    const ushort* __restrict__ qkv, ushort* __restrict__ Kts,
    ushort* __restrict__ Vt, const float* __restrict__ dlogit)
{
    __shared__ ushort tile[64][72];
    __shared__ float dp[64];
    const int tid = threadIdx.x;
    const int t0 = blockIdx.x * 64, c0 = blockIdx.y * 64;
    const int b = blockIdx.z >> 1, mat = blockIdx.z & 1;  // 0=K, 1=V
    const float d = dsigmoid(dlogit);
    if (tid < 64) dp[tid] = powf(d, (float)tid);
    const int coff = 256 + mat * 256 + c0;
#pragma unroll
    for (int j = 0; j < 2; ++j) {
        int row = (tid >> 3) + j * 32;
        int seg = (tid & 7) * 8;
        *(int4*)&tile[row][seg] =
            *(const int4*)(qkv + ((size_t)(b * Tt + t0 + row)) * QLD + coff + seg);
    }
    __syncthreads();
    const int cl = tid & 63, tb = (tid >> 6) * 16;
    ushort* outp = (mat ? Vt : Kts) + ((size_t)(b * Cc + c0 + cl)) * Tt + t0 + tb;
#pragma unroll
    for (int h = 0; h < 2; ++h) {
        union { ushort us[8]; int4 v; } o;
#pragma unroll
        for (int jj = 0; jj < 8; ++jj) {
            int tl = tb + h * 8 + jj;
            ushort val = tile[tl][cl];
            if (mat == 0) val = f2bf(bf2f(val) * dp[tl]);
            o.us[jj] = val;
        }
        *(int4*)(outp + h * 8) = o.v;
    }
}

// ---------------------------------------------------------------- chunk outer products (MFMA)
// LT[b][g][c][c'] = sum_s Vt[c][s] * Kts[c'][s]  (= L[c'][c]), bf16 out.
__global__ __launch_bounds__(256) void chunk_lt(
    const ushort* __restrict__ Kts, const ushort* __restrict__ Vt,
    ushort* __restrict__ LT)
{
    const int tid = threadIdx.x;
    const int g = blockIdx.y, b = blockIdx.z;
    const int c0 = (blockIdx.x & 1) * 128, cp0 = (blockIdx.x >> 1) * 128;
    const int w = tid >> 6, l = tid & 63;
    const int wc = (w >> 1) * 64, wcp = (w & 1) * 64;
    const int lrow = l & 15, lk = l >> 4;

    f32x4 acc[4][4];
#pragma unroll
    for (int mi = 0; mi < 4; ++mi)
#pragma unroll
        for (int ni = 0; ni < 4; ++ni) {
            f32x4 z = {0.f, 0.f, 0.f, 0.f};
            acc[mi][ni] = z;
        }
#pragma unroll
    for (int ks = 0; ks < 2; ++ks) {
        short8 af[4], bf[4];
#pragma unroll
        for (int mi = 0; mi < 4; ++mi)
            af[mi] = *(const short8*)(Vt +
                ((size_t)(b * Cc + c0 + wc + mi * 16 + lrow)) * Tt + g * TC + ks * 32 + lk * 8);
#pragma unroll
        for (int ni = 0; ni < 4; ++ni)
            bf[ni] = *(const short8*)(Kts +
                ((size_t)(b * Cc + cp0 + wcp + ni * 16 + lrow)) * Tt + g * TC + ks * 32 + lk * 8);
#pragma unroll
        for (int mi = 0; mi < 4; ++mi)
#pragma unroll
            for (int ni = 0; ni < 4; ++ni)
                acc[mi][ni] = __builtin_amdgcn_mfma_f32_16x16x32_bf16(
                    af[mi], bf[ni], acc[mi][ni], 0, 0, 0);
    }
    ushort* lb = LT + (((size_t)(b * Gg + g)) << 16);
#pragma unroll
    for (int mi = 0; mi < 4; ++mi)
#pragma unroll
        for (int ni = 0; ni < 4; ++ni)
#pragma unroll
            for (int r = 0; r < 4; ++r)
                lb[(size_t)(c0 + wc + mi * 16 + lk * 4 + r) * Cc + cp0 + wcp + ni * 16 + lrow]
                    = f2bf(acc[mi][ni][r]);
}

// ---------------------------------------------------------------- reverse scan
// j = Gg-1..1:  cur = LT[j] + d^Tc*cur ; SbT[j-1] = cur.   4-deep load batches.
__global__ __launch_bounds__(64) void scan_kernel(
    const ushort* __restrict__ LT, ushort* __restrict__ SbT,
    const float* __restrict__ dlogit)
{
    const int e = blockIdx.x * 64 + threadIdx.x;
    const int b = blockIdx.y;
    const float d = dsigmoid(dlogit);
    const float dTc = powf(d, (float)TC);
    const size_t CC = (size_t)Cc * Cc;
    const size_t base = (size_t)b * Gg * CC + e;
    SbT[base + (size_t)(Gg - 1) * CC] = 0;
    float cur = 0.f;
    int j = Gg - 1;
    for (; j >= 4; j -= 4) {
        ushort l0 = LT[base + (size_t)j * CC];
        ushort l1 = LT[base + (size_t)(j - 1) * CC];
        ushort l2 = LT[base + (size_t)(j - 2) * CC];
        ushort l3 = LT[base + (size_t)(j - 3) * CC];
        cur = bf2f(l0) + dTc * cur; SbT[base + (size_t)(j - 1) * CC] = f2bf(cur);
        cur = bf2f(l1) + dTc * cur; SbT[base + (size_t)(j - 2) * CC] = f2bf(cur);
        cur = bf2f(l2) + dTc * cur; SbT[base + (size_t)(j - 3) * CC] = f2bf(cur);
        cur = bf2f(l3) + dTc * cur; SbT[base + (size_t)(j - 4) * CC] = f2bf(cur);
    }
    for (; j >= 1; --j) {
        cur = bf2f(LT[base + (size_t)j * CC]) + dTc * cur;
        SbT[base + (size_t)(j - 1) * CC] = f2bf(cur);
    }
}

// ---------------------------------------------------------------- attention (MFMA)
// One block per (g,b), 4 waves. retr[64,256] =
//   P @ V  (P[t][s] = (s>t) d^{s-t-1} q_t.k_s)  +  d^{63-t} * (Q @ SbT rows)
__global__ __launch_bounds__(256) void attn_mfma(
    const ushort* __restrict__ qkv, const ushort* __restrict__ SbT,
    const ushort* __restrict__ Vt, ushort* __restrict__ retrb,
    const float* __restrict__ dlogit)
{
    __shared__ ushort Qsm[64][264];
    __shared__ ushort Ksm[64][264];
    __shared__ ushort Psm[64][72];
    __shared__ float dpow[64];
    const int tid = threadIdx.x;
    const int g = blockIdx.x, b = blockIdx.y;
    const float d = dsigmoid(dlogit);
    if (tid < 64) dpow[tid] = powf(d, (float)tid);

    const ushort* qb = qkv + ((size_t)(b * Tt + g * TC)) * QLD;
#pragma unroll
    for (int j = 0; j < 8; ++j) {
        int seg = tid + 256 * j;
        int row = seg >> 5, sc = (seg & 31) * 8;
        *(int4*)&Qsm[row][sc] = *(const int4*)(qb + (size_t)row * QLD + sc);
        *(int4*)&Ksm[row][sc] = *(const int4*)(qb + (size_t)row * QLD + 256 + sc);
    }
    __syncthreads();

    const int w = tid >> 6, l = tid & 63;
    const int lrow = l & 15, lk = l >> 4;

    // ---- QK^T: wave w computes P cols [w*16, w*16+16)
    f32x4 acc1[4];
#pragma unroll
    for (int mi = 0; mi < 4; ++mi) { f32x4 z = {0.f,0.f,0.f,0.f}; acc1[mi] = z; }
#pragma unroll
    for (int ks = 0; ks < 8; ++ks) {
        short8 bf = *(const short8*)&Ksm[w * 16 + lrow][ks * 32 + lk * 8];
#pragma unroll
        for (int mi = 0; mi < 4; ++mi) {
            short8 af = *(const short8*)&Qsm[mi * 16 + lrow][ks * 32 + lk * 8];
            acc1[mi] = __builtin_amdgcn_mfma_f32_16x16x32_bf16(af, bf, acc1[mi], 0, 0, 0);
        }
    }
#pragma unroll
    for (int mi = 0; mi < 4; ++mi)
#pragma unroll
        for (int r = 0; r < 4; ++r) {
            int t = mi * 16 + lk * 4 + r, s = w * 16 + lrow;
            float p = (s > t) ? acc1[mi][r] * dpow[s - t - 1] : 0.f;
            Psm[t][s] = f2bf(p);
        }
    __syncthreads();

    // ---- retr accumulator: wave w covers cols [w*64, w*64+64)
    f32x4 acc[4][4];
#pragma unroll
    for (int mi = 0; mi < 4; ++mi)
#pragma unroll
        for (int ni = 0; ni < 4; ++ni) {
            f32x4 z = {0.f, 0.f, 0.f, 0.f};
            acc[mi][ni] = z;
        }

    // part B: Q @ S (SbT rows are S columns), K=256
    const ushort* Sg = SbT + (((size_t)(b * Gg + g)) << 16);
#pragma unroll
    for (int ks = 0; ks < 8; ++ks) {
        short8 af[4], bf[4];
#pragma unroll
        for (int mi = 0; mi < 4; ++mi)
            af[mi] = *(const short8*)&Qsm[mi * 16 + lrow][ks * 32 + lk * 8];
#pragma unroll
        for (int ni = 0; ni < 4; ++ni)
            bf[ni] = *(const short8*)(Sg +
                (size_t)(w * 64 + ni * 16 + lrow) * Cc + ks * 32 + lk * 8);
#pragma unroll
        for (int mi = 0; mi < 4; ++mi)
#pragma unroll
            for (int ni = 0; ni < 4; ++ni)
                acc[mi][ni] = __builtin_amdgcn_mfma_f32_16x16x32_bf16(
                    af[mi], bf[ni], acc[mi][ni], 0, 0, 0);
    }
    // scale inter-chunk term by d^{63 - t}
#pragma unroll
    for (int mi = 0; mi < 4; ++mi) {
#pragma unroll
        for (int r = 0; r < 4; ++r) {
            float wq = dpow[63 - (mi * 16 + lk * 4 + r)];
#pragma unroll
            for (int ni = 0; ni < 4; ++ni) acc[mi][ni][r] *= wq;
        }
    }
    // part A: P @ Vt, K=64
#pragma unroll
    for (int ks = 0; ks < 2; ++ks) {
        short8 af[4], bf[4];
#pragma unroll
        for (int mi = 0; mi < 4; ++mi)
            af[mi] = *(const short8*)&Psm[mi * 16 + lrow][ks * 32 + lk * 8];
#pragma unroll
        for (int ni = 0; ni < 4; ++ni)
            bf[ni] = *(const short8*)(Vt +
                ((size_t)(b * Cc + w * 64 + ni * 16 + lrow)) * Tt + g * TC + ks * 32 + lk * 8);
#pragma unroll
        for (int mi = 0; mi < 4; ++mi)
#pragma unroll
            for (int ni = 0; ni < 4; ++ni)
                acc[mi][ni] = __builtin_amdgcn_mfma_f32_16x16x32_bf16(
                    af[mi], bf[ni], acc[mi][ni], 0, 0, 0);
    }

    ushort* rb = retrb + ((size_t)(b * Tt + g * TC)) * Cc;
#pragma unroll
    for (int mi = 0; mi < 4; ++mi)
#pragma unroll
        for (int ni = 0; ni < 4; ++ni)
#pragma unroll
            for (int r = 0; r < 4; ++r)
                rb[(size_t)(mi * 16 + lk * 4 + r) * Cc + w * 64 + ni * 16 + lrow]
                    = f2bf(acc[mi][ni][r]);
}

// ---------------------------------------------------------------- launch
extern "C" void kernel_launch(void* const* d_in, const int* in_sizes, int n_in,
                              void* d_out, int out_size, void* d_ws, size_t ws_size,
                              hipStream_t stream) {
    const float* x      = (const float*)d_in[0];
    const float* basis  = (const float*)d_in[1];
    const float* qc     = (const float*)d_in[2];
    const float* kc     = (const float*)d_in[3];
    const float* vc     = (const float*)d_in[4];
    const float* oc     = (const float*)d_in[5];
    const float* dlogit = (const float*)d_in[6];
    const float* oscale = (const float*)d_in[7];
    float* out = (float*)d_out;

    char* w = (char*)d_ws;
    ushort* basisb  = (ushort*)w;  w += (size_t)Vv * Ff * 2;          // 256KB
    ushort* qkvc    = (ushort*)w;  w += (size_t)768 * Ff * 2;         // 192KB
    ushort* ocb     = (ushort*)w;  w += (size_t)Cc * Ff * 2;          // 64KB
    ushort* ow      = (ushort*)w;  w += (size_t)Vv * Cc * 2;          // 512KB
    ushort* Wq      = (ushort*)w;  w += (size_t)768 * Vv * 2;         // 1.5MB
    ushort* xbf     = (ushort*)w;  w += (size_t)Bb * Tt * Vv * 2;     // 33.5MB
    ushort* qkv     = (ushort*)w;  w += (size_t)Bb * Tt * QLD * 2;    // 25MB
    ushort* Kts     = (ushort*)w;  w += (size_t)Bb * Cc * Tt * 2;     // 8.4MB
    ushort* Vt      = (ushort*)w;  w += (size_t)Bb * Cc * Tt * 2;     // 8.4MB
    ushort* SbT     = (ushort*)w;  w += (size_t)Bb * Gg * Cc * Cc * 2;// 33.5MB
    ushort* retrb   = (ushort*)w;  w += (size_t)Bb * Tt * Cc * 2;     // 8.4MB
    ushort* LT      = xbf;  // 33.5MB, xbf dead after qkv GEMM (same size)

    convert_x<<<2048, 256, 0, stream>>>(x, xbf);
    prep_weights<<<512, 256, 0, stream>>>(basis, qc, kc, vc, oc, basisb, qkvc, ocb);
    // Wq[ch][v] = qkvc[ch].basisb[v] : M=768 N=1024 K=128
    ggemm<0><<<dim3(6, 8), 256, 0, stream>>>(qkvc, basisb, Wq, Vv, Ff, Ff, nullptr);
    // ow[v][c] = basisb[v].ocb[c] : M=1024 N=256 K=128
    ggemm<0><<<dim3(8, 2), 256, 0, stream>>>(basisb, ocb, ow, Cc, Ff, Ff, nullptr);
    // qkv = xbf @ Wq^T : M=16384 N=768 K=1024
    ggemm<0><<<dim3(128, 6), 256, 0, stream>>>(xbf, Wq, qkv, QLD, Vv, Vv, nullptr);
    // K/V transpose (+decay pre-scale on K)
    transpose_kv<<<dim3(Tt / 64, Cc / 64, Bb * 2), 256, 0, stream>>>(qkv, Kts, Vt, dlogit);
    // per-chunk outer products (MFMA) -> LT bf16  (aliases dead xbf)
    chunk_lt<<<dim3(4, Gg, Bb), 256, 0, stream>>>(Kts, Vt, LT);
    // reverse scan -> SbT bf16
    scan_kernel<<<dim3(Cc * Cc / 64, Bb), 64, 0, stream>>>(LT, SbT, dlogit);
    // attention core (MFMA) -> retr bf16
    attn_mfma<<<dim3(Gg, Bb), 256, 0, stream>>>(qkv, SbT, Vt, retrb, dlogit);
    // out = retr @ ow^T * out_scale : M=16384 N=1024 K=256
    ggemm<1><<<dim3(128, 8), 256, 0, stream>>>(retrb, ow, out, Vv, Cc, Cc, oscale);
}

// Round 9
// 250.055 us; speedup vs baseline: 1.0826x; 1.0826x over previous
//
#include <hip/hip_runtime.h>

// AssociativeMemoryStep — chunked linear attention, fully MFMA.
// Round 9: + T2 LDS XOR-swizzle in ggemm (rule #21: linear global_load_lds
// dest, pre-swizzled global SOURCE column, swizzled READ col). Fixes the
// 9.4M-conflict 16-lane/bank-group pattern of the 128B-row linear tile.
// B=4 T=4096 V=1024 F=128 C=256, chunk Tc=64 (G=64).

#define Bb 4
#define Tt 4096
#define Vv 1024
#define Ff 128
#define Cc 256
#define TC 64
#define Gg (Tt / TC)
#define QLD 768  // q|k|v row stride (elements)

typedef __attribute__((ext_vector_type(8))) short short8;
typedef __attribute__((ext_vector_type(4))) float f32x4;

__device__ __forceinline__ float dsigmoid(const float* p) {
    return 1.0f / (1.0f + expf(-p[0]));
}
__device__ __forceinline__ ushort f2bf(float f) {
    unsigned u = __float_as_uint(f);
    u = (u + 0x7FFFu + ((u >> 16) & 1u)) >> 16;
    return (ushort)u;
}
__device__ __forceinline__ float bf2f(ushort u) {
    return __uint_as_float(((unsigned)u) << 16);
}
__device__ __forceinline__ void gl_lds16(ushort* lds, const ushort* gp) {
    __builtin_amdgcn_global_load_lds(
        (const __attribute__((address_space(1))) unsigned int*)gp,
        (__attribute__((address_space(3))) unsigned int*)lds,
        16, 0, 0);
}

// ---------------------------------------------------------------- x -> bf16
__global__ __launch_bounds__(256) void convert_x(
    const float* __restrict__ x, ushort* __restrict__ xbf)
{
    const size_t total = (size_t)Bb * Tt * Vv;
    for (size_t i = ((size_t)blockIdx.x * 256 + threadIdx.x) * 8; i < total;
         i += (size_t)2048 * 256 * 8) {
        float4 a = *(const float4*)(x + i);
        float4 b = *(const float4*)(x + i + 4);
        union { ushort us[8]; int4 v; } o;
        o.us[0] = f2bf(a.x); o.us[1] = f2bf(a.y); o.us[2] = f2bf(a.z); o.us[3] = f2bf(a.w);
        o.us[4] = f2bf(b.x); o.us[5] = f2bf(b.y); o.us[6] = f2bf(b.z); o.us[7] = f2bf(b.w);
        *(int4*)(xbf + i) = o.v;
    }
}

// ---------------------------------------------------------------- weight prep
__global__ __launch_bounds__(256) void prep_weights(
    const float* __restrict__ basis, const float* __restrict__ qc,
    const float* __restrict__ kc, const float* __restrict__ vc,
    const float* __restrict__ oc,
    ushort* __restrict__ basisb,    // [1024][128] bf16 (straight convert)
    ushort* __restrict__ qkvc,      // [768][128]  bf16 concat(qc,kc,vc)
    ushort* __restrict__ ocb)       // [256][128]  bf16
{
    int i = blockIdx.x * 256 + threadIdx.x;
    if (i < Vv * Ff) basisb[i] = f2bf(basis[i]);
    if (i < 768 * Ff) {
        int ch = i >> 7;
        const float* src = ch < 256 ? qc : (ch < 512 ? kc : vc);
        qkvc[i] = f2bf(src[(ch & 255) * Ff + (i & 127)]);
    }
    if (i < Cc * Ff) ocb[i] = f2bf(oc[i]);
}

// ---------------------------------------------------------------- MFMA GEMM (m97 + T2 swizzle)
// C[M,N] = A[M,K] @ Bt[N,K]^T, A/Bt bf16 K-major. BM=BN=128, BK=64,
// 4 waves (2x2), 64x64/wave, global_load_lds width=16.
// Swizzle involution (short idx within row): col ^= (row&7)<<3. LDS dest is
// linear (gl_lds constraint); the global SOURCE col carries the inverse
// permutation; reads apply the same XOR. Frag-read lanes then hit bank-slot
// lk^(lrow&7): uniform 8 lanes/group (optimal) instead of 16.
// OMODE: 0 = bf16 out, 1 = fp32 out * alpha.
template<int OMODE>
__global__ __launch_bounds__(256) void ggemm(
    const ushort* __restrict__ A, const ushort* __restrict__ Bt,
    void* __restrict__ Cp, int N_total, int K_total, int ldA,
    const float* __restrict__ alpha_ptr)
{
    __shared__ ushort Asm[128 * 64];
    __shared__ ushort Bsm[128 * 64];
    const int tid = threadIdx.x;
    const int row0 = blockIdx.x * 128, col0 = blockIdx.y * 128;
    const int l = tid & 63, w = tid >> 6;
    const int wr = (w >> 1) * 64, wc = (w & 1) * 64;
    const int lrow = l & 15, lk = l >> 4;
    const int lkey = (lrow & 7) << 3;          // read-side swizzle key

    f32x4 acc[4][4];
#pragma unroll
    for (int mi = 0; mi < 4; ++mi)
#pragma unroll
        for (int ni = 0; ni < 4; ++ni) {
            f32x4 z = {0.f, 0.f, 0.f, 0.f};
            acc[mi][ni] = z;
        }

    // stage-side: linear LDS slot (r, c) receives global col c ^ ((r&7)<<3)
    const int sia = threadIdx.x * 8;           // base short-index this thread
    const int sr = sia >> 6, sc = sia & 63;
    const int scs = sc ^ ((sr & 7) << 3);      // pre-swizzled source col

    for (int k0 = 0; k0 < K_total; k0 += 64) {
#pragma unroll
        for (int call = 0; call < 4; ++call) {
            int ia = sia + call * 2048;        // +32 rows per call, col fixed
            int r = sr + call * 32;
            gl_lds16(&Asm[ia], A + (size_t)(row0 + r) * ldA + k0 + scs);
            gl_lds16(&Bsm[ia], Bt + (size_t)(col0 + r) * K_total + k0 + scs);
        }
        __syncthreads();                       // drains vmcnt -> LDS ready
#pragma unroll
        for (int ks = 0; ks < 2; ++ks) {
            short8 af[4], bf[4];
#pragma unroll
            for (int mi = 0; mi < 4; ++mi)
                af[mi] = *(const short8*)&Asm[(wr + mi * 16 + lrow) * 64 +
                                              ((ks * 32 + lk * 8) ^ lkey)];
#pragma unroll
            for (int ni = 0; ni < 4; ++ni)
                bf[ni] = *(const short8*)&Bsm[(wc + ni * 16 + lrow) * 64 +
                                              ((ks * 32 + lk * 8) ^ lkey)];
#pragma unroll
            for (int mi = 0; mi < 4; ++mi)
#pragma unroll
                for (int ni = 0; ni < 4; ++ni)
                    acc[mi][ni] = __builtin_amdgcn_mfma_f32_16x16x32_bf16(
                        af[mi], bf[ni], acc[mi][ni], 0, 0, 0);
        }
        __syncthreads();
    }

    const float alpha = (OMODE == 1) ? alpha_ptr[0] : 1.0f;
#pragma unroll
    for (int mi = 0; mi < 4; ++mi)
#pragma unroll
        for (int ni = 0; ni < 4; ++ni)
#pragma unroll
            for (int r = 0; r < 4; ++r) {
                int row = row0 + wr + mi * 16 + lk * 4 + r;
                int col = col0 + wc + ni * 16 + lrow;
                size_t idx = (size_t)row * N_total + col;
                if (OMODE == 1) ((float*)Cp)[idx] = acc[mi][ni][r] * alpha;
                else ((ushort*)Cp)[idx] = f2bf(acc[mi][ni][r]);
            }
}

// ---------------------------------------------------------------- K/V transpose
// Kts[b][c][t] = d^{t&63} * K[b][t][c] ; Vt[b][c][t] = V[b][t][c]  (bf16)
__global__ __launch_bounds__(256) void transpose_kv(
    const ushort* __restrict__ qkv, ushort* __restrict__ Kts,
    ushort* __restrict__ Vt, const float* __restrict__ dlogit)
{
    __shared__ ushort tile[64][72];
    __shared__ float dp[64];
    const int tid = threadIdx.x;
    const int t0 = blockIdx.x * 64, c0 = blockIdx.y * 64;
    const int b = blockIdx.z >> 1, mat = blockIdx.z & 1;  // 0=K, 1=V
    const float d = dsigmoid(dlogit);
    if (tid < 64) dp[tid] = powf(d, (float)tid);
    const int coff = 256 + mat * 256 + c0;
#pragma unroll
    for (int j = 0; j < 2; ++j) {
        int row = (tid >> 3) + j * 32;
        int seg = (tid & 7) * 8;
        *(int4*)&tile[row][seg] =
            *(const int4*)(qkv + ((size_t)(b * Tt + t0 + row)) * QLD + coff + seg);
    }
    __syncthreads();
    const int cl = tid & 63, tb = (tid >> 6) * 16;
    ushort* outp = (mat ? Vt : Kts) + ((size_t)(b * Cc + c0 + cl)) * Tt + t0 + tb;
#pragma unroll
    for (int h = 0; h < 2; ++h) {
        union { ushort us[8]; int4 v; } o;
#pragma unroll
        for (int jj = 0; jj < 8; ++jj) {
            int tl = tb + h * 8 + jj;
            ushort val = tile[tl][cl];
            if (mat == 0) val = f2bf(bf2f(val) * dp[tl]);
            o.us[jj] = val;
        }
        *(int4*)(outp + h * 8) = o.v;
    }
}

// ---------------------------------------------------------------- chunk outer products (MFMA)
// LT[b][g][c][c'] = sum_s Vt[c][s] * Kts[c'][s]  (= L[c'][c]), bf16 out.
__global__ __launch_bounds__(256) void chunk_lt(
    const ushort* __restrict__ Kts, const ushort* __restrict__ Vt,
    ushort* __restrict__ LT)
{
    const int tid = threadIdx.x;
    const int g = blockIdx.y, b = blockIdx.z;
    const int c0 = (blockIdx.x & 1) * 128, cp0 = (blockIdx.x >> 1) * 128;
    const int w = tid >> 6, l = tid & 63;
    const int wc = (w >> 1) * 64, wcp = (w & 1) * 64;
    const int lrow = l & 15, lk = l >> 4;

    f32x4 acc[4][4];
#pragma unroll
    for (int mi = 0; mi < 4; ++mi)
#pragma unroll
        for (int ni = 0; ni < 4; ++ni) {
            f32x4 z = {0.f, 0.f, 0.f, 0.f};
            acc[mi][ni] = z;
        }
#pragma unroll
    for (int ks = 0; ks < 2; ++ks) {
        short8 af[4], bf[4];
#pragma unroll
        for (int mi = 0; mi < 4; ++mi)
            af[mi] = *(const short8*)(Vt +
                ((size_t)(b * Cc + c0 + wc + mi * 16 + lrow)) * Tt + g * TC + ks * 32 + lk * 8);
#pragma unroll
        for (int ni = 0; ni < 4; ++ni)
            bf[ni] = *(const short8*)(Kts +
                ((size_t)(b * Cc + cp0 + wcp + ni * 16 + lrow)) * Tt + g * TC + ks * 32 + lk * 8);
#pragma unroll
        for (int mi = 0; mi < 4; ++mi)
#pragma unroll
            for (int ni = 0; ni < 4; ++ni)
                acc[mi][ni] = __builtin_amdgcn_mfma_f32_16x16x32_bf16(
                    af[mi], bf[ni], acc[mi][ni], 0, 0, 0);
    }
    ushort* lb = LT + (((size_t)(b * Gg + g)) << 16);
#pragma unroll
    for (int mi = 0; mi < 4; ++mi)
#pragma unroll
        for (int ni = 0; ni < 4; ++ni)
#pragma unroll
            for (int r = 0; r < 4; ++r)
                lb[(size_t)(c0 + wc + mi * 16 + lk * 4 + r) * Cc + cp0 + wcp + ni * 16 + lrow]
                    = f2bf(acc[mi][ni][r]);
}

// ---------------------------------------------------------------- reverse scan
// j = Gg-1..1:  cur = LT[j] + d^Tc*cur ; SbT[j-1] = cur.   4-deep load batches.
__global__ __launch_bounds__(64) void scan_kernel(
    const ushort* __restrict__ LT, ushort* __restrict__ SbT,
    const float* __restrict__ dlogit)
{
    const int e = blockIdx.x * 64 + threadIdx.x;
    const int b = blockIdx.y;
    const float d = dsigmoid(dlogit);
    const float dTc = powf(d, (float)TC);
    const size_t CC = (size_t)Cc * Cc;
    const size_t base = (size_t)b * Gg * CC + e;
    SbT[base + (size_t)(Gg - 1) * CC] = 0;
    float cur = 0.f;
    int j = Gg - 1;
    for (; j >= 4; j -= 4) {
        ushort l0 = LT[base + (size_t)j * CC];
        ushort l1 = LT[base + (size_t)(j - 1) * CC];
        ushort l2 = LT[base + (size_t)(j - 2) * CC];
        ushort l3 = LT[base + (size_t)(j - 3) * CC];
        cur = bf2f(l0) + dTc * cur; SbT[base + (size_t)(j - 1) * CC] = f2bf(cur);
        cur = bf2f(l1) + dTc * cur; SbT[base + (size_t)(j - 2) * CC] = f2bf(cur);
        cur = bf2f(l2) + dTc * cur; SbT[base + (size_t)(j - 3) * CC] = f2bf(cur);
        cur = bf2f(l3) + dTc * cur; SbT[base + (size_t)(j - 4) * CC] = f2bf(cur);
    }
    for (; j >= 1; --j) {
        cur = bf2f(LT[base + (size_t)j * CC]) + dTc * cur;
        SbT[base + (size_t)(j - 1) * CC] = f2bf(cur);
    }
}

// ---------------------------------------------------------------- attention (MFMA)
// One block per (g,b), 4 waves. retr[64,256] =
//   P @ V  (P[t][s] = (s>t) d^{s-t-1} q_t.k_s)  +  d^{63-t} * (Q @ SbT rows)
__global__ __launch_bounds__(256) void attn_mfma(
    const ushort* __restrict__ qkv, const ushort* __restrict__ SbT,
    const ushort* __restrict__ Vt, ushort* __restrict__ retrb,
    const float* __restrict__ dlogit)
{
    __shared__ ushort Qsm[64][264];
    __shared__ ushort Ksm[64][264];
    __shared__ ushort Psm[64][72];
    __shared__ float dpow[64];
    const int tid = threadIdx.x;
    const int g = blockIdx.x, b = blockIdx.y;
    const float d = dsigmoid(dlogit);
    if (tid < 64) dpow[tid] = powf(d, (float)tid);

    const ushort* qb = qkv + ((size_t)(b * Tt + g * TC)) * QLD;
#pragma unroll
    for (int j = 0; j < 8; ++j) {
        int seg = tid + 256 * j;
        int row = seg >> 5, sc = (seg & 31) * 8;
        *(int4*)&Qsm[row][sc] = *(const int4*)(qb + (size_t)row * QLD + sc);
        *(int4*)&Ksm[row][sc] = *(const int4*)(qb + (size_t)row * QLD + 256 + sc);
    }
    __syncthreads();

    const int w = tid >> 6, l = tid & 63;
    const int lrow = l & 15, lk = l >> 4;

    // ---- QK^T: wave w computes P cols [w*16, w*16+16)
    f32x4 acc1[4];
#pragma unroll
    for (int mi = 0; mi < 4; ++mi) { f32x4 z = {0.f,0.f,0.f,0.f}; acc1[mi] = z; }
#pragma unroll
    for (int ks = 0; ks < 8; ++ks) {
        short8 bf = *(const short8*)&Ksm[w * 16 + lrow][ks * 32 + lk * 8];
#pragma unroll
        for (int mi = 0; mi < 4; ++mi) {
            short8 af = *(const short8*)&Qsm[mi * 16 + lrow][ks * 32 + lk * 8];
            acc1[mi] = __builtin_amdgcn_mfma_f32_16x16x32_bf16(af, bf, acc1[mi], 0, 0, 0);
        }
    }
#pragma unroll
    for (int mi = 0; mi < 4; ++mi)
#pragma unroll
        for (int r = 0; r < 4; ++r) {
            int t = mi * 16 + lk * 4 + r, s = w * 16 + lrow;
            float p = (s > t) ? acc1[mi][r] * dpow[s - t - 1] : 0.f;
            Psm[t][s] = f2bf(p);
        }
    __syncthreads();

    // ---- retr accumulator: wave w covers cols [w*64, w*64+64)
    f32x4 acc[4][4];
#pragma unroll
    for (int mi = 0; mi < 4; ++mi)
#pragma unroll
        for (int ni = 0; ni < 4; ++ni) {
            f32x4 z = {0.f, 0.f, 0.f, 0.f};
            acc[mi][ni] = z;
        }

    // part B: Q @ S (SbT rows are S columns), K=256
    const ushort* Sg = SbT + (((size_t)(b * Gg + g)) << 16);
#pragma unroll
    for (int ks = 0; ks < 8; ++ks) {
        short8 af[4], bf[4];
#pragma unroll
        for (int mi = 0; mi < 4; ++mi)
            af[mi] = *(const short8*)&Qsm[mi * 16 + lrow][ks * 32 + lk * 8];
#pragma unroll
        for (int ni = 0; ni < 4; ++ni)
            bf[ni] = *(const short8*)(Sg +
                (size_t)(w * 64 + ni * 16 + lrow) * Cc + ks * 32 + lk * 8);
#pragma unroll
        for (int mi = 0; mi < 4; ++mi)
#pragma unroll
            for (int ni = 0; ni < 4; ++ni)
                acc[mi][ni] = __builtin_amdgcn_mfma_f32_16x16x32_bf16(
                    af[mi], bf[ni], acc[mi][ni], 0, 0, 0);
    }
    // scale inter-chunk term by d^{63 - t}
#pragma unroll
    for (int mi = 0; mi < 4; ++mi) {
#pragma unroll
        for (int r = 0; r < 4; ++r) {
            float wq = dpow[63 - (mi * 16 + lk * 4 + r)];
#pragma unroll
            for (int ni = 0; ni < 4; ++ni) acc[mi][ni][r] *= wq;
        }
    }
    // part A: P @ Vt, K=64
#pragma unroll
    for (int ks = 0; ks < 2; ++ks) {
        short8 af[4], bf[4];
#pragma unroll
        for (int mi = 0; mi < 4; ++mi)
            af[mi] = *(const short8*)&Psm[mi * 16 + lrow][ks * 32 + lk * 8];
#pragma unroll
        for (int ni = 0; ni < 4; ++ni)
            bf[ni] = *(const short8*)(Vt +
                ((size_t)(b * Cc + w * 64 + ni * 16 + lrow)) * Tt + g * TC + ks * 32 + lk * 8);
#pragma unroll
        for (int mi = 0; mi < 4; ++mi)
#pragma unroll
            for (int ni = 0; ni < 4; ++ni)
                acc[mi][ni] = __builtin_amdgcn_mfma_f32_16x16x32_bf16(
                    af[mi], bf[ni], acc[mi][ni], 0, 0, 0);
    }

    ushort* rb = retrb + ((size_t)(b * Tt + g * TC)) * Cc;
#pragma unroll
    for (int mi = 0; mi < 4; ++mi)
#pragma unroll
        for (int ni = 0; ni < 4; ++ni)
#pragma unroll
            for (int r = 0; r < 4; ++r)
                rb[(size_t)(mi * 16 + lk * 4 + r) * Cc + w * 64 + ni * 16 + lrow]
                    = f2bf(acc[mi][ni][r]);
}

// ---------------------------------------------------------------- launch
extern "C" void kernel_launch(void* const* d_in, const int* in_sizes, int n_in,
                              void* d_out, int out_size, void* d_ws, size_t ws_size,
                              hipStream_t stream) {
    const float* x      = (const float*)d_in[0];
    const float* basis  = (const float*)d_in[1];
    const float* qc     = (const float*)d_in[2];
    const float* kc     = (const float*)d_in[3];
    const float* vc     = (const float*)d_in[4];
    const float* oc     = (const float*)d_in[5];
    const float* dlogit = (const float*)d_in[6];
    const float* oscale = (const float*)d_in[7];
    float* out = (float*)d_out;

    char* w = (char*)d_ws;
    ushort* basisb  = (ushort*)w;  w += (size_t)Vv * Ff * 2;          // 256KB
    ushort* qkvc    = (ushort*)w;  w += (size_t)768 * Ff * 2;         // 192KB
    ushort* ocb     = (ushort*)w;  w += (size_t)Cc * Ff * 2;          // 64KB
    ushort* ow      = (ushort*)w;  w += (size_t)Vv * Cc * 2;          // 512KB
    ushort* Wq      = (ushort*)w;  w += (size_t)768 * Vv * 2;         // 1.5MB
    ushort* xbf     = (ushort*)w;  w += (size_t)Bb * Tt * Vv * 2;     // 33.5MB
    ushort* qkv     = (ushort*)w;  w += (size_t)Bb * Tt * QLD * 2;    // 25MB
    ushort* Kts     = (ushort*)w;  w += (size_t)Bb * Cc * Tt * 2;     // 8.4MB
    ushort* Vt      = (ushort*)w;  w += (size_t)Bb * Cc * Tt * 2;     // 8.4MB
    ushort* SbT     = (ushort*)w;  w += (size_t)Bb * Gg * Cc * Cc * 2;// 33.5MB
    ushort* retrb   = (ushort*)w;  w += (size_t)Bb * Tt * Cc * 2;     // 8.4MB
    ushort* LT      = xbf;  // 33.5MB, xbf dead after qkv GEMM (same size)

    convert_x<<<2048, 256, 0, stream>>>(x, xbf);
    prep_weights<<<512, 256, 0, stream>>>(basis, qc, kc, vc, oc, basisb, qkvc, ocb);
    // Wq[ch][v] = qkvc[ch].basisb[v] : M=768 N=1024 K=128
    ggemm<0><<<dim3(6, 8), 256, 0, stream>>>(qkvc, basisb, Wq, Vv, Ff, Ff, nullptr);
    // ow[v][c] = basisb[v].ocb[c] : M=1024 N=256 K=128
    ggemm<0><<<dim3(8, 2), 256, 0, stream>>>(basisb, ocb, ow, Cc, Ff, Ff, nullptr);
    // qkv = xbf @ Wq^T : M=16384 N=768 K=1024
    ggemm<0><<<dim3(128, 6), 256, 0, stream>>>(xbf, Wq, qkv, QLD, Vv, Vv, nullptr);
    // K/V transpose (+decay pre-scale on K)
    transpose_kv<<<dim3(Tt / 64, Cc / 64, Bb * 2), 256, 0, stream>>>(qkv, Kts, Vt, dlogit);
    // per-chunk outer products (MFMA) -> LT bf16  (aliases dead xbf)
    chunk_lt<<<dim3(4, Gg, Bb), 256, 0, stream>>>(Kts, Vt, LT);
    // reverse scan -> SbT bf16
    scan_kernel<<<dim3(Cc * Cc / 64, Bb), 64, 0, stream>>>(LT, SbT, dlogit);
    // attention core (MFMA) -> retr bf16
    attn_mfma<<<dim3(Gg, Bb), 256, 0, stream>>>(qkv, SbT, Vt, retrb, dlogit);
    // out = retr @ ow^T * out_scale : M=16384 N=1024 K=256
    ggemm<1><<<dim3(128, 8), 256, 0, stream>>>(retrb, ow, out, Vv, Cc, Cc, oscale);
}